// Round 8
// baseline (237.071 us; speedup 1.0000x reference)
//
#include <hip/hip_runtime.h>
#include <hip/hip_fp16.h>

constexpr int N      = 100000;
constexpr int E      = 3200000;
constexpr int IN_CH  = 128;
constexpr int HID    = 16;
constexpr int OUT_CH = 64;

constexpr int NPB    = 128;                  // nodes per bucket
constexpr int NB     = (N + NPB - 1) / NPB;  // 782 buckets
constexpr int PBLK   = 2048;                 // partition blocks (8/CU)
constexpr int CHUNK  = (E + PBLK - 1) / PBLK;// 1563
constexpr int RPT    = PBLK / 256;           // rows per thread in column scan

typedef float nfloat4 __attribute__((ext_vector_type(4)));  // native vec for NT builtins

// ---- pass A: per-block bucket histogram ----
__global__ __launch_bounds__(256) void k_hist(const int* __restrict__ ei,
                                              unsigned* __restrict__ pbc) {
    __shared__ unsigned cnt[NB];
    int k = blockIdx.x, t = threadIdx.x;
    for (int b = t; b < NB; b += 256) cnt[b] = 0;
    __syncthreads();
    const int* dst = ei + E;
    int e0 = k * CHUNK, e1 = min(e0 + CHUNK, E);
    for (int e = e0 + t; e < e1; e += 256)
        atomicAdd(&cnt[((unsigned)__builtin_nontemporal_load(dst + e)) >> 7], 1u);
    __syncthreads();
    for (int b = t; b < NB; b += 256) pbc[(size_t)k * NB + b] = cnt[b];
}

// ---- pass B: column scan over 2048 rows: 256 threads x 8 values ----
__global__ __launch_bounds__(256) void k_scan_cols(unsigned* __restrict__ pbc,
                                                   unsigned* __restrict__ tot) {
    __shared__ unsigned s[256];
    int b = blockIdx.x, t = threadIdx.x;
    unsigned v[RPT];
    unsigned sum = 0;
    #pragma unroll
    for (int i = 0; i < RPT; ++i) {
        v[i] = pbc[(size_t)(t * RPT + i) * NB + b];
        sum += v[i];
    }
    s[t] = sum;
    __syncthreads();
    for (int off = 1; off < 256; off <<= 1) {
        unsigned u = (t >= off) ? s[t - off] : 0u;
        __syncthreads();
        s[t] += u;
        __syncthreads();
    }
    unsigned ex = s[t] - sum;                // exclusive across thread groups
    #pragma unroll
    for (int i = 0; i < RPT; ++i) {
        pbc[(size_t)(t * RPT + i) * NB + b] = ex;
        ex += v[i];
    }
    if (t == 255) tot[b] = s[255];
}

// ---- pass C: scan bucket totals ----
__global__ __launch_bounds__(1024) void k_scan_tot(const unsigned* __restrict__ tot,
                                                   unsigned* __restrict__ base) {
    __shared__ unsigned s[1024];
    int t = threadIdx.x;
    unsigned v = (t < NB) ? tot[t] : 0u;
    s[t] = v;
    __syncthreads();
    for (int off = 1; off < 1024; off <<= 1) {
        unsigned u = (t >= off) ? s[t - off] : 0u;
        __syncthreads();
        s[t] += u;
        __syncthreads();
    }
    if (t < NB) base[t] = s[t] - v;
    if (t == 1023) base[NB] = s[t];
}

// ---- pass D: partition edges into buckets ----
__global__ __launch_bounds__(256) void k_partition(const int* __restrict__ ei,
                                                   const unsigned* __restrict__ pbc,
                                                   const unsigned* __restrict__ base,
                                                   unsigned* __restrict__ packed) {
    __shared__ unsigned gcur[NB];
    int k = blockIdx.x, t = threadIdx.x;
    for (int b = t; b < NB; b += 256)
        gcur[b] = base[b] + pbc[(size_t)k * NB + b];
    __syncthreads();
    int e0 = k * CHUNK, e1 = min(e0 + CHUNK, E);
    for (int e = e0 + t; e < e1; e += 256) {
        unsigned s = (unsigned)__builtin_nontemporal_load(ei + e);
        unsigned d = (unsigned)__builtin_nontemporal_load(ei + E + e);
        unsigned b = d >> 7, dl = d & 127u;
        unsigned slot = atomicAdd(&gcur[b], 1u);
        packed[slot] = (dl << 17) | s;       // src<2^17, dl<2^7
    }
}

// ---- pass E: per-bucket counting sort -> sorted_src, node_start, dinv ----
__global__ __launch_bounds__(512) void k_sort(const unsigned* __restrict__ packed,
                                              const unsigned* __restrict__ base,
                                              unsigned* __restrict__ sorted,
                                              unsigned* __restrict__ node_start,
                                              float* __restrict__ dinv) {
    __shared__ unsigned cnt[NPB];
    __shared__ unsigned pref[NPB];
    __shared__ unsigned cur[NPB];
    int b = blockIdx.x, t = threadIdx.x;
    if (t < NPB) cnt[t] = 0;
    __syncthreads();
    unsigned e0 = base[b], e1 = base[b + 1];
    for (unsigned e = e0 + t; e < e1; e += 512)
        atomicAdd(&cnt[__builtin_nontemporal_load(packed + e) >> 17], 1u);
    __syncthreads();
    if (t < NPB) pref[t] = cnt[t];
    __syncthreads();
    for (int off = 1; off < NPB; off <<= 1) {
        unsigned u = (t < NPB && t >= off) ? pref[t - off] : 0u;
        __syncthreads();
        if (t < NPB) pref[t] += u;           // inclusive scan
        __syncthreads();
    }
    if (t < NPB) {
        unsigned ex = pref[t] - cnt[t];
        cur[t] = ex;
        int node = b * NPB + t;
        if (node < N) {
            node_start[node] = e0 + ex;
            dinv[node] = rsqrtf((float)cnt[t] + 1.0f);
        }
    }
    if (b == NB - 1 && t == 0) node_start[N] = e1;
    __syncthreads();
    for (unsigned e = e0 + t; e < e1; e += 512) {
        unsigned p = __builtin_nontemporal_load(packed + e);
        unsigned slot = e0 + atomicAdd(&cur[p >> 17], 1u);
        sorted[slot] = p & 0x1FFFFu;
    }
}

// ---- layer1 linear: h1s = fp16(dinv * (x @ W1)) ----
__global__ __launch_bounds__(256) void k_lin1(const float* __restrict__ x,
                                              const float* __restrict__ W1,
                                              const float* __restrict__ dinv,
                                              __half* __restrict__ h1s) {
    __shared__ float W1T[HID][IN_CH + 4];
    __shared__ float xs[16][IN_CH + 4];
    int t = threadIdx.x;
    for (int i = t; i < IN_CH * HID; i += 256) {
        int k = i >> 4, c = i & 15;
        W1T[c][k] = W1[i];
    }
    int rb = blockIdx.x * 16;
    const float4* xblk = (const float4*)(x + (size_t)rb * IN_CH);
    for (int i4 = t; i4 < 16 * IN_CH / 4; i4 += 256) {
        int r = i4 >> 5, c4 = i4 & 31;
        *(float4*)&xs[r][c4 * 4] = xblk[i4];
    }
    __syncthreads();

    int r = t >> 4, c = t & 15;
    int row = rb + r;
    const float4* xr = (const float4*)xs[r];
    const float4* wr = (const float4*)W1T[c];
    float acc = 0.f;
    #pragma unroll
    for (int k4 = 0; k4 < IN_CH / 4; ++k4) {
        float4 a = xr[k4], w = wr[k4];
        acc += a.x * w.x + a.y * w.y + a.z * w.z + a.w * w.w;
    }
    __half hv = __float2half_rn(dinv[row] * acc);
    __builtin_nontemporal_store(*(const unsigned short*)&hv,
                                (unsigned short*)(h1s + (size_t)row * HID + c));
}

__device__ __forceinline__ void accum8(float* acc, const float4& raw) {
    const __half2* hp = (const __half2*)&raw;
    #pragma unroll
    for (int j = 0; j < 4; ++j) {
        float2 f = __half22float2(hp[j]);
        acc[2 * j] += f.x;
        acc[2 * j + 1] += f.y;
    }
}

// ================== aggregation: 8 nodes/wave, 8 lanes/node =================
// lane = nw*8 + eslot*2 + half;  nw in [0,8), eslot in [0,4), half in {0,1}

// ---- layer1 agg: h2s[d] = fp16(dinv*relu(dinv*(sum h1s[src] + h1s[d]) + b1)) ----
__global__ __launch_bounds__(256) void k_agg1(const unsigned* __restrict__ sorted,
                                              const unsigned* __restrict__ ns,
                                              const float* __restrict__ dinv,
                                              const __half* __restrict__ h1s,
                                              const float* __restrict__ b1,
                                              __half* __restrict__ h2s) {
    int t = threadIdx.x;
    int wave = (blockIdx.x << 2) + (t >> 6);     // global wave id
    int lane = t & 63;
    int nw = lane >> 3, slot = lane & 7;
    int eslot = slot >> 1, half = slot & 1;
    int wid = (wave << 3) + nw;                  // node, uniform per 8-lane group
    unsigned s0 = ns[wid], s1 = ns[wid + 1];
    float di = dinv[wid];
    float4 bb = *(const float4*)(b1 + half * 8);
    float4 bb2 = *(const float4*)(b1 + half * 8 + 4);
    float4 selfraw = *(const float4*)(h1s + (size_t)wid * HID + half * 8);

    float acc[8];
    {   // self-loop carried by eslot==0 lanes
        const __half2* hp = (const __half2*)&selfraw;
        float m = (eslot == 0) ? 1.f : 0.f;
        #pragma unroll
        for (int j = 0; j < 4; ++j) {
            float2 f = __half22float2(hp[j]);
            acc[2 * j] = m * f.x;
            acc[2 * j + 1] = m * f.y;
        }
    }
    unsigned e = s0 + eslot;
    bool valid = e < s1;
    unsigned src = valid ? __builtin_nontemporal_load(sorted + e) : 0u;
    while (__any((int)valid)) {
        unsigned e2 = e + 4;
        bool valid2 = e2 < s1;
        unsigned src2 = valid2 ? __builtin_nontemporal_load(sorted + e2) : 0u;
        if (valid) {
            float4 raw = *(const float4*)(h1s + (size_t)src * HID + half * 8);
            accum8(acc, raw);
        }
        e = e2; valid = valid2; src = src2;
    }
    #pragma unroll
    for (int j = 0; j < 8; ++j) acc[j] += __shfl_xor(acc[j], 2, 64);
    #pragma unroll
    for (int j = 0; j < 8; ++j) acc[j] += __shfl_xor(acc[j], 4, 64);

    if (eslot == 0) {
        float bv[8] = {bb.x, bb.y, bb.z, bb.w, bb2.x, bb2.y, bb2.z, bb2.w};
        __half2 tmp[4];
        #pragma unroll
        for (int j = 0; j < 4; ++j) {
            float o0 = di * fmaxf(di * acc[2 * j] + bv[2 * j], 0.f);
            float o1 = di * fmaxf(di * acc[2 * j + 1] + bv[2 * j + 1], 0.f);
            tmp[j] = __float22half2_rn(float2{o0, o1});
        }
        nfloat4 ow = *(const nfloat4*)tmp;
        __builtin_nontemporal_store(ow, (nfloat4*)(h2s + (size_t)wid * HID + half * 8));
    }
}

// ---- layer2 agg (gather only): hag[d] = fp16(dinv[d]*(sum h2s[src] + h2s[d])) ----
__global__ __launch_bounds__(256) void k_agg2(const unsigned* __restrict__ sorted,
                                              const unsigned* __restrict__ ns,
                                              const float* __restrict__ dinv,
                                              const __half* __restrict__ h2s,
                                              __half* __restrict__ hag) {
    int t = threadIdx.x;
    int wave = (blockIdx.x << 2) + (t >> 6);
    int lane = t & 63;
    int nw = lane >> 3, slot = lane & 7;
    int eslot = slot >> 1, half = slot & 1;
    int wid = (wave << 3) + nw;
    unsigned s0 = ns[wid], s1 = ns[wid + 1];
    float di = dinv[wid];
    float4 selfraw = *(const float4*)(h2s + (size_t)wid * HID + half * 8);

    float acc[8];
    {
        const __half2* hp = (const __half2*)&selfraw;
        float m = (eslot == 0) ? 1.f : 0.f;
        #pragma unroll
        for (int j = 0; j < 4; ++j) {
            float2 f = __half22float2(hp[j]);
            acc[2 * j] = m * f.x;
            acc[2 * j + 1] = m * f.y;
        }
    }
    unsigned e = s0 + eslot;
    bool valid = e < s1;
    unsigned src = valid ? __builtin_nontemporal_load(sorted + e) : 0u;
    while (__any((int)valid)) {
        unsigned e2 = e + 4;
        bool valid2 = e2 < s1;
        unsigned src2 = valid2 ? __builtin_nontemporal_load(sorted + e2) : 0u;
        if (valid) {
            float4 raw = *(const float4*)(h2s + (size_t)src * HID + half * 8);
            accum8(acc, raw);
        }
        e = e2; valid = valid2; src = src2;
    }
    #pragma unroll
    for (int j = 0; j < 8; ++j) acc[j] += __shfl_xor(acc[j], 2, 64);
    #pragma unroll
    for (int j = 0; j < 8; ++j) acc[j] += __shfl_xor(acc[j], 4, 64);

    if (eslot == 0) {
        __half2 tmp[4];
        #pragma unroll
        for (int j = 0; j < 4; ++j)
            tmp[j] = __float22half2_rn(float2{di * acc[2 * j], di * acc[2 * j + 1]});
        nfloat4 ow = *(const nfloat4*)tmp;
        __builtin_nontemporal_store(ow, (nfloat4*)(hag + (size_t)wid * HID + half * 8));
    }
}

// ---- layer2 linear: out = hag @ W2 + b2 (dense, coalesced) ----
__global__ __launch_bounds__(256) void k_lin2(const __half* __restrict__ hag,
                                              const float* __restrict__ W2,
                                              const float* __restrict__ b2,
                                              float* __restrict__ out) {
    __shared__ float W2s[HID * OUT_CH];   // 4 KB
    __shared__ float as[16][HID];
    int t = threadIdx.x;
    for (int i = t; i < HID * OUT_CH; i += 256) W2s[i] = W2[i];
    int rb = blockIdx.x * 16;
    as[t >> 4][t & 15] = __half2float(hag[(size_t)rb * HID + t]);
    __syncthreads();

    int r = t >> 4;
    int c4 = (t & 15) * 4;
    int row = rb + r;
    float4 acc = *(const float4*)&b2[c4];
    #pragma unroll
    for (int k = 0; k < HID; ++k) {
        float a = as[r][k];
        const float* w = &W2s[k * OUT_CH + c4];
        acc.x += a * w[0]; acc.y += a * w[1]; acc.z += a * w[2]; acc.w += a * w[3];
    }
    nfloat4 o = {acc.x, acc.y, acc.z, acc.w};
    __builtin_nontemporal_store(o, (nfloat4*)(out + (size_t)row * OUT_CH + c4));
}

extern "C" void kernel_launch(void* const* d_in, const int* in_sizes, int n_in,
                              void* d_out, int out_size, void* d_ws, size_t ws_size,
                              hipStream_t stream) {
    const float* x  = (const float*)d_in[0];
    const int*   ei = (const int*)d_in[1];
    const float* W1 = (const float*)d_in[2];
    const float* b1 = (const float*)d_in[3];
    const float* W2 = (const float*)d_in[4];
    const float* b2 = (const float*)d_in[5];
    float* out = (float*)d_out;

    char* ws = (char*)d_ws;
    float*    dinv   = (float*)(ws);                    // N f32
    unsigned* node_start = (unsigned*)(ws + 524288);    // (N+1) u32
    unsigned* tot    = (unsigned*)(ws + 1048576);       // NB u32
    unsigned* base   = (unsigned*)(ws + 1056768);       // NB+1 u32
    unsigned* packed = (unsigned*)(ws + 2097152);       // E u32, dead after k_sort
    __half*   h1s    = (__half*)(ws + 2097152);         // 3.2MB — overlays packed
    __half*   h2s    = (__half*)(ws + 5505024);         // 3.2MB — overlays packed
    __half*   hag    = (__half*)(ws + 8912896);         // 3.2MB — overlays packed
    unsigned* sorted = (unsigned*)(ws + 14897152);      // E u32 [14.9MB..27.7MB)
    // pbc (PBLK*NB u32 = 6.4MB) overlays the *sorted* region: pbc is dead after
    // k_partition, sorted is first written by k_sort — lifetimes disjoint.
    unsigned* pbc    = (unsigned*)(ws + 14897152);

    k_hist      <<<PBLK, 256, 0, stream>>>(ei, pbc);
    k_scan_cols <<<NB, 256, 0, stream>>>(pbc, tot);
    k_scan_tot  <<<1, 1024, 0, stream>>>(tot, base);
    k_partition <<<PBLK, 256, 0, stream>>>(ei, pbc, base, packed);
    k_sort      <<<NB, 512, 0, stream>>>(packed, base, sorted, node_start, dinv);
    k_lin1      <<<N / 16, 256, 0, stream>>>(x, W1, dinv, h1s);
    k_agg1      <<<N / 32, 256, 0, stream>>>(sorted, node_start, dinv, h1s, b1, h2s);
    k_agg2      <<<N / 32, 256, 0, stream>>>(sorted, node_start, dinv, h2s, hag);
    k_lin2      <<<N / 16, 256, 0, stream>>>(hag, W2, b2, out);
}

// Round 9
// 163.723 us; speedup vs baseline: 1.4480x; 1.4480x over previous
//
#include <hip/hip_runtime.h>
#include <hip/hip_fp16.h>

constexpr int N      = 100000;
constexpr int E      = 3200000;
constexpr int IN_CH  = 128;
constexpr int HID    = 16;
constexpr int OUT_CH = 64;

constexpr int NPB    = 128;                  // nodes per bucket
constexpr int NB     = (N + NPB - 1) / NPB;  // 782 buckets
constexpr int PBLK   = 256;                  // partition blocks
constexpr int CHUNK  = E / PBLK;             // 12500 exactly
static_assert(E % PBLK == 0, "uniform chunks");
constexpr int PTHR   = 1024;                 // threads in hist/partition blocks
constexpr int NITER  = (CHUNK + PTHR - 1) / PTHR;  // 13

typedef float nfloat4 __attribute__((ext_vector_type(4)));  // native vec for NT builtins

// ---- pass A: per-block bucket histogram (1024 thr, 16 waves/CU) ----
__global__ __launch_bounds__(1024) void k_hist(const int* __restrict__ ei,
                                               unsigned* __restrict__ pbc) {
    __shared__ unsigned cnt[NB];
    int k = blockIdx.x, t = threadIdx.x;
    for (int b = t; b < NB; b += PTHR) cnt[b] = 0;
    __syncthreads();
    const int* dst = ei + E;
    int e0 = k * CHUNK;
    for (int e = e0 + t; e < e0 + CHUNK; e += PTHR)
        atomicAdd(&cnt[((unsigned)__builtin_nontemporal_load(dst + e)) >> 7], 1u);
    __syncthreads();
    for (int b = t; b < NB; b += PTHR) pbc[(size_t)k * NB + b] = cnt[b];
}

// ---- pass B: column scan (PBLK=256 rows) ----
__global__ __launch_bounds__(256) void k_scan_cols(unsigned* __restrict__ pbc,
                                                   unsigned* __restrict__ tot) {
    __shared__ unsigned s[PBLK];
    int b = blockIdx.x, t = threadIdx.x;
    unsigned v = pbc[(size_t)t * NB + b];
    s[t] = v;
    __syncthreads();
    for (int off = 1; off < PBLK; off <<= 1) {
        unsigned u = (t >= off) ? s[t - off] : 0u;
        __syncthreads();
        s[t] += u;
        __syncthreads();
    }
    pbc[(size_t)t * NB + b] = s[t] - v;      // exclusive
    if (t == PBLK - 1) tot[b] = s[t];
}

// ---- pass C: scan bucket totals ----
__global__ __launch_bounds__(1024) void k_scan_tot(const unsigned* __restrict__ tot,
                                                   unsigned* __restrict__ base) {
    __shared__ unsigned s[1024];
    int t = threadIdx.x;
    unsigned v = (t < NB) ? tot[t] : 0u;
    s[t] = v;
    __syncthreads();
    for (int off = 1; off < 1024; off <<= 1) {
        unsigned u = (t >= off) ? s[t - off] : 0u;
        __syncthreads();
        s[t] += u;
        __syncthreads();
    }
    if (t < NB) base[t] = s[t] - v;
    if (t == 1023) base[NB] = s[t];
}

// ---- pass D: partition with LDS write-combining (block counting sort) ----
__global__ __launch_bounds__(1024) void k_partition(const int* __restrict__ ei,
                                                    const unsigned* __restrict__ pbc,
                                                    const unsigned* __restrict__ base,
                                                    unsigned* __restrict__ packed) {
    __shared__ unsigned staged[CHUNK];       // 50.0 KB bucket-sorted payloads
    __shared__ unsigned short sb[CHUNK];     // 25.0 KB bucket id per slot
    __shared__ unsigned cnt[NB];             // 3.1 KB
    __shared__ unsigned pref[NB];            // 3.1 KB exclusive prefix
    __shared__ unsigned cur[NB];             // 3.1 KB cursors
    __shared__ unsigned goff[NB];            // 3.1 KB global offset per bucket
    __shared__ unsigned s[PTHR];             // 4.0 KB scan temp

    int k = blockIdx.x, t = threadIdx.x;
    for (int b = t; b < NB; b += PTHR) cnt[b] = 0;
    __syncthreads();

    int e0 = k * CHUNK;
    unsigned vq[NITER];
    unsigned short bq[NITER];
    // pass 1: read edges into registers, count buckets (fully unrolled -> regs)
    #pragma unroll
    for (int i = 0; i < NITER; ++i) {
        int idx = t + i * PTHR;
        if (i < NITER - 1 || idx < CHUNK) {
            int e = e0 + idx;
            unsigned sv = (unsigned)__builtin_nontemporal_load(ei + e);
            unsigned d  = (unsigned)__builtin_nontemporal_load(ei + E + e);
            unsigned b  = d >> 7;
            vq[i] = ((d & 127u) << 17) | sv;
            bq[i] = (unsigned short)b;
            atomicAdd(&cnt[b], 1u);
        }
    }
    __syncthreads();

    // block scan over cnt[NB]
    unsigned own = (t < NB) ? cnt[t] : 0u;
    s[t] = own;
    __syncthreads();
    for (int off = 1; off < PTHR; off <<= 1) {
        unsigned u = (t >= off) ? s[t - off] : 0u;
        __syncthreads();
        s[t] += u;
        __syncthreads();
    }
    if (t < NB) {
        unsigned ex = s[t] - own;
        pref[t] = ex;
        cur[t]  = ex;
        goff[t] = base[t] + pbc[(size_t)k * NB + t] - ex;
    }
    __syncthreads();

    // pass 2: scatter into bucket-sorted LDS staging
    #pragma unroll
    for (int i = 0; i < NITER; ++i) {
        int idx = t + i * PTHR;
        if (i < NITER - 1 || idx < CHUNK) {
            unsigned b = bq[i];
            unsigned slot = atomicAdd(&cur[b], 1u);
            staged[slot] = vq[i];
            sb[slot] = (unsigned short)b;
        }
    }
    __syncthreads();

    // writeout: consecutive lanes -> consecutive global addresses within runs
    for (int i = t; i < CHUNK; i += PTHR) {
        unsigned b = sb[i];
        packed[goff[b] + i] = staged[i];
    }
}

// ---- pass E: per-bucket counting sort -> sorted_src, node_start, dinv ----
__global__ __launch_bounds__(512) void k_sort(const unsigned* __restrict__ packed,
                                              const unsigned* __restrict__ base,
                                              unsigned* __restrict__ sorted,
                                              unsigned* __restrict__ node_start,
                                              float* __restrict__ dinv) {
    __shared__ unsigned cnt[NPB];
    __shared__ unsigned pref[NPB];
    __shared__ unsigned cur[NPB];
    int b = blockIdx.x, t = threadIdx.x;
    if (t < NPB) cnt[t] = 0;
    __syncthreads();
    unsigned e0 = base[b], e1 = base[b + 1];
    for (unsigned e = e0 + t; e < e1; e += 512)
        atomicAdd(&cnt[__builtin_nontemporal_load(packed + e) >> 17], 1u);
    __syncthreads();
    if (t < NPB) pref[t] = cnt[t];
    __syncthreads();
    for (int off = 1; off < NPB; off <<= 1) {
        unsigned u = (t < NPB && t >= off) ? pref[t - off] : 0u;
        __syncthreads();
        if (t < NPB) pref[t] += u;           // inclusive scan
        __syncthreads();
    }
    if (t < NPB) {
        unsigned ex = pref[t] - cnt[t];
        cur[t] = ex;
        int node = b * NPB + t;
        if (node < N) {
            node_start[node] = e0 + ex;
            dinv[node] = rsqrtf((float)cnt[t] + 1.0f);
        }
    }
    if (b == NB - 1 && t == 0) node_start[N] = e1;
    __syncthreads();
    for (unsigned e = e0 + t; e < e1; e += 512) {
        unsigned p = __builtin_nontemporal_load(packed + e);
        unsigned slot = e0 + atomicAdd(&cur[p >> 17], 1u);
        sorted[slot] = p & 0x1FFFFu;
    }
}

// ---- layer1 linear: h1s = fp16(dinv * (x @ W1)) ----
__global__ __launch_bounds__(256) void k_lin1(const float* __restrict__ x,
                                              const float* __restrict__ W1,
                                              const float* __restrict__ dinv,
                                              __half* __restrict__ h1s) {
    __shared__ float W1T[HID][IN_CH + 4];
    __shared__ float xs[16][IN_CH + 4];
    int t = threadIdx.x;
    for (int i = t; i < IN_CH * HID; i += 256) {
        int k = i >> 4, c = i & 15;
        W1T[c][k] = W1[i];
    }
    int rb = blockIdx.x * 16;
    const float4* xblk = (const float4*)(x + (size_t)rb * IN_CH);
    for (int i4 = t; i4 < 16 * IN_CH / 4; i4 += 256) {
        int r = i4 >> 5, c4 = i4 & 31;
        *(float4*)&xs[r][c4 * 4] = xblk[i4];
    }
    __syncthreads();

    int r = t >> 4, c = t & 15;
    int row = rb + r;
    const float4* xr = (const float4*)xs[r];
    const float4* wr = (const float4*)W1T[c];
    float acc = 0.f;
    #pragma unroll
    for (int k4 = 0; k4 < IN_CH / 4; ++k4) {
        float4 a = xr[k4], w = wr[k4];
        acc += a.x * w.x + a.y * w.y + a.z * w.z + a.w * w.w;
    }
    __half hv = __float2half_rn(dinv[row] * acc);
    __builtin_nontemporal_store(*(const unsigned short*)&hv,
                                (unsigned short*)(h1s + (size_t)row * HID + c));
}

__device__ __forceinline__ void accum8(float* acc, const float4& raw) {
    const __half2* hp = (const __half2*)&raw;
    #pragma unroll
    for (int j = 0; j < 4; ++j) {
        float2 f = __half22float2(hp[j]);
        acc[2 * j] += f.x;
        acc[2 * j + 1] += f.y;
    }
}

// ================== aggregation: 8 nodes/wave, 8 lanes/node =================
// lane = nw*8 + eslot*2 + half;  nw in [0,8), eslot in [0,4), half in {0,1}

// ---- layer1 agg: h2s[d] = fp16(dinv*relu(dinv*(sum h1s[src] + h1s[d]) + b1)) ----
__global__ __launch_bounds__(256) void k_agg1(const unsigned* __restrict__ sorted,
                                              const unsigned* __restrict__ ns,
                                              const float* __restrict__ dinv,
                                              const __half* __restrict__ h1s,
                                              const float* __restrict__ b1,
                                              __half* __restrict__ h2s) {
    int t = threadIdx.x;
    int wave = (blockIdx.x << 2) + (t >> 6);     // global wave id
    int lane = t & 63;
    int nw = lane >> 3, slot = lane & 7;
    int eslot = slot >> 1, half = slot & 1;
    int wid = (wave << 3) + nw;                  // node, uniform per 8-lane group
    unsigned s0 = ns[wid], s1 = ns[wid + 1];
    float di = dinv[wid];
    float4 bb = *(const float4*)(b1 + half * 8);
    float4 bb2 = *(const float4*)(b1 + half * 8 + 4);
    float4 selfraw = *(const float4*)(h1s + (size_t)wid * HID + half * 8);

    float acc[8];
    {   // self-loop carried by eslot==0 lanes
        const __half2* hp = (const __half2*)&selfraw;
        float m = (eslot == 0) ? 1.f : 0.f;
        #pragma unroll
        for (int j = 0; j < 4; ++j) {
            float2 f = __half22float2(hp[j]);
            acc[2 * j] = m * f.x;
            acc[2 * j + 1] = m * f.y;
        }
    }
    unsigned e = s0 + eslot;
    bool valid = e < s1;
    unsigned src = valid ? __builtin_nontemporal_load(sorted + e) : 0u;
    while (__any((int)valid)) {
        unsigned e2 = e + 4;
        bool valid2 = e2 < s1;
        unsigned src2 = valid2 ? __builtin_nontemporal_load(sorted + e2) : 0u;
        if (valid) {
            float4 raw = *(const float4*)(h1s + (size_t)src * HID + half * 8);
            accum8(acc, raw);
        }
        e = e2; valid = valid2; src = src2;
    }
    #pragma unroll
    for (int j = 0; j < 8; ++j) acc[j] += __shfl_xor(acc[j], 2, 64);
    #pragma unroll
    for (int j = 0; j < 8; ++j) acc[j] += __shfl_xor(acc[j], 4, 64);

    if (eslot == 0) {
        float bv[8] = {bb.x, bb.y, bb.z, bb.w, bb2.x, bb2.y, bb2.z, bb2.w};
        __half2 tmp[4];
        #pragma unroll
        for (int j = 0; j < 4; ++j) {
            float o0 = di * fmaxf(di * acc[2 * j] + bv[2 * j], 0.f);
            float o1 = di * fmaxf(di * acc[2 * j + 1] + bv[2 * j + 1], 0.f);
            tmp[j] = __float22half2_rn(float2{o0, o1});
        }
        nfloat4 ow = *(const nfloat4*)tmp;
        __builtin_nontemporal_store(ow, (nfloat4*)(h2s + (size_t)wid * HID + half * 8));
    }
}

// ---- layer2 agg (gather only): hag[d] = fp16(dinv[d]*(sum h2s[src] + h2s[d])) ----
__global__ __launch_bounds__(256) void k_agg2(const unsigned* __restrict__ sorted,
                                              const unsigned* __restrict__ ns,
                                              const float* __restrict__ dinv,
                                              const __half* __restrict__ h2s,
                                              __half* __restrict__ hag) {
    int t = threadIdx.x;
    int wave = (blockIdx.x << 2) + (t >> 6);
    int lane = t & 63;
    int nw = lane >> 3, slot = lane & 7;
    int eslot = slot >> 1, half = slot & 1;
    int wid = (wave << 3) + nw;
    unsigned s0 = ns[wid], s1 = ns[wid + 1];
    float di = dinv[wid];
    float4 selfraw = *(const float4*)(h2s + (size_t)wid * HID + half * 8);

    float acc[8];
    {
        const __half2* hp = (const __half2*)&selfraw;
        float m = (eslot == 0) ? 1.f : 0.f;
        #pragma unroll
        for (int j = 0; j < 4; ++j) {
            float2 f = __half22float2(hp[j]);
            acc[2 * j] = m * f.x;
            acc[2 * j + 1] = m * f.y;
        }
    }
    unsigned e = s0 + eslot;
    bool valid = e < s1;
    unsigned src = valid ? __builtin_nontemporal_load(sorted + e) : 0u;
    while (__any((int)valid)) {
        unsigned e2 = e + 4;
        bool valid2 = e2 < s1;
        unsigned src2 = valid2 ? __builtin_nontemporal_load(sorted + e2) : 0u;
        if (valid) {
            float4 raw = *(const float4*)(h2s + (size_t)src * HID + half * 8);
            accum8(acc, raw);
        }
        e = e2; valid = valid2; src = src2;
    }
    #pragma unroll
    for (int j = 0; j < 8; ++j) acc[j] += __shfl_xor(acc[j], 2, 64);
    #pragma unroll
    for (int j = 0; j < 8; ++j) acc[j] += __shfl_xor(acc[j], 4, 64);

    if (eslot == 0) {
        __half2 tmp[4];
        #pragma unroll
        for (int j = 0; j < 4; ++j)
            tmp[j] = __float22half2_rn(float2{di * acc[2 * j], di * acc[2 * j + 1]});
        nfloat4 ow = *(const nfloat4*)tmp;
        __builtin_nontemporal_store(ow, (nfloat4*)(hag + (size_t)wid * HID + half * 8));
    }
}

// ---- layer2 linear: out = hag @ W2 + b2 (dense, coalesced) ----
__global__ __launch_bounds__(256) void k_lin2(const __half* __restrict__ hag,
                                              const float* __restrict__ W2,
                                              const float* __restrict__ b2,
                                              float* __restrict__ out) {
    __shared__ float W2s[HID * OUT_CH];   // 4 KB
    __shared__ float as[16][HID];
    int t = threadIdx.x;
    for (int i = t; i < HID * OUT_CH; i += 256) W2s[i] = W2[i];
    int rb = blockIdx.x * 16;
    as[t >> 4][t & 15] = __half2float(hag[(size_t)rb * HID + t]);
    __syncthreads();

    int r = t >> 4;
    int c4 = (t & 15) * 4;
    int row = rb + r;
    float4 acc = *(const float4*)&b2[c4];
    #pragma unroll
    for (int k = 0; k < HID; ++k) {
        float a = as[r][k];
        const float* w = &W2s[k * OUT_CH + c4];
        acc.x += a * w[0]; acc.y += a * w[1]; acc.z += a * w[2]; acc.w += a * w[3];
    }
    nfloat4 o = {acc.x, acc.y, acc.z, acc.w};
    __builtin_nontemporal_store(o, (nfloat4*)(out + (size_t)row * OUT_CH + c4));
}

extern "C" void kernel_launch(void* const* d_in, const int* in_sizes, int n_in,
                              void* d_out, int out_size, void* d_ws, size_t ws_size,
                              hipStream_t stream) {
    const float* x  = (const float*)d_in[0];
    const int*   ei = (const int*)d_in[1];
    const float* W1 = (const float*)d_in[2];
    const float* b1 = (const float*)d_in[3];
    const float* W2 = (const float*)d_in[4];
    const float* b2 = (const float*)d_in[5];
    float* out = (float*)d_out;

    char* ws = (char*)d_ws;
    float*    dinv   = (float*)(ws);                    // N f32
    unsigned* node_start = (unsigned*)(ws + 524288);    // (N+1) u32
    unsigned* tot    = (unsigned*)(ws + 1048576);       // NB u32
    unsigned* base   = (unsigned*)(ws + 1056768);       // NB+1 u32
    unsigned* pbc    = (unsigned*)(ws + 1064960);       // PBLK*NB u32 = 800KB
    unsigned* packed = (unsigned*)(ws + 2097152);       // E u32, dead after k_sort
    __half*   h1s    = (__half*)(ws + 2097152);         // 3.2MB — overlays packed
    __half*   h2s    = (__half*)(ws + 5505024);         // 3.2MB — overlays packed
    __half*   hag    = (__half*)(ws + 8912896);         // 3.2MB — overlays packed
    unsigned* sorted = (unsigned*)(ws + 14897152);      // E u32 [14.9MB..27.7MB)

    k_hist      <<<PBLK, PTHR, 0, stream>>>(ei, pbc);
    k_scan_cols <<<NB, PBLK, 0, stream>>>(pbc, tot);
    k_scan_tot  <<<1, 1024, 0, stream>>>(tot, base);
    k_partition <<<PBLK, PTHR, 0, stream>>>(ei, pbc, base, packed);
    k_sort      <<<NB, 512, 0, stream>>>(packed, base, sorted, node_start, dinv);
    k_lin1      <<<N / 16, 256, 0, stream>>>(x, W1, dinv, h1s);
    k_agg1      <<<N / 32, 256, 0, stream>>>(sorted, node_start, dinv, h1s, b1, h2s);
    k_agg2      <<<N / 32, 256, 0, stream>>>(sorted, node_start, dinv, h2s, hag);
    k_lin2      <<<N / 16, 256, 0, stream>>>(hag, W2, b2, out);
}